// Round 11
// baseline (507.844 us; speedup 1.0000x reference)
//
#include <hip/hip_runtime.h>
#include <hip/hip_bf16.h>

#define Bb 8
#define Tt 48
#define HZ 24
#define Nn 1024
#define Hh 512
#define NHEAD 8

typedef short short8 __attribute__((ext_vector_type(8)));
typedef short bf16x4 __attribute__((ext_vector_type(4)));
typedef float f32x4 __attribute__((ext_vector_type(4)));

__device__ __forceinline__ ushort f2bf(float f) {
  uint u = __builtin_bit_cast(uint, f);
  u += 0x7FFFu + ((u >> 16) & 1u);
  return (ushort)(u >> 16);
}

// K=16 bf16 MFMA: lane l holds B[k=g*4+reg][col=l&15]; acc C-layout matches.
__device__ __forceinline__ f32x4 mfma16(bf16x4 a, bf16x4 b, f32x4 c) {
#if __has_builtin(__builtin_amdgcn_mfma_f32_16x16x16bf16_1k)
  return __builtin_amdgcn_mfma_f32_16x16x16bf16_1k(a, b, c, 0, 0, 0);
#elif __has_builtin(__builtin_amdgcn_mfma_f32_16x16x16_bf16)
  return __builtin_amdgcn_mfma_f32_16x16x16_bf16(a, b, c, 0, 0, 0);
#else
  f32x4 d;
  asm volatile("v_mfma_f32_16x16x16_bf16 %0, %1, %2, %3\n\ts_nop 7\n\ts_nop 4"
               : "=v"(d) : "v"(a), "v"(b), "v"(c));
  return d;
#endif
}

// ---- prep: repack Wv into per-lane MFMA fragment order ----
// W2[ch][w][kb][f=ki*2+nn][lane][e]  (ushort), 512KB total.
__global__ void wvt2_kernel(const float* __restrict__ Wv, ushort* __restrict__ W2) {
  int t = blockIdx.x * 256 + threadIdx.x;    // [0, 262144)
  int e = t & 7;
  int lane = (t >> 3) & 63;
  int f = (t >> 9) & 3;
  int kb = (t >> 11) & 7;
  int w = (t >> 14) & 3;
  int ch = t >> 16;
  int ki = f >> 1, nn = f & 1;
  int row = ch * 128 + w * 32 + nn * 16 + (lane & 15);
  int col = kb * 64 + ki * 32 + ((lane >> 4) << 3) + e;
  W2[t] = f2bf(Wv[col * 512 + row]);
}

// ---- prep: attention weights (fp32 softmax) -> bf16 padded [B][8][32][64] ----
__global__ void attn_kernel(const float* __restrict__ xt, const float* __restrict__ tt,
                            const float* __restrict__ Wq, const float* __restrict__ bq,
                            const float* __restrict__ Wk, const float* __restrict__ bk,
                            ushort* __restrict__ attnp) {
  __shared__ float qs[24][65];
  __shared__ float ks_[48][65];
  __shared__ float sc[24][49];
  int bh = blockIdx.x;                       // 64 blocks
  int b = bh >> 3, h = bh & 7;
  int t = threadIdx.x;
  for (int e = t; e < 24 * 64; e += 256) {
    int i = e >> 6, dd = e & 63;
    float s = bq[h * 64 + dd];
    const float* r = tt + (b * 24 + i) * 64;
    #pragma unroll 8
    for (int c = 0; c < 64; ++c) s += r[c] * Wq[c * 512 + h * 64 + dd];
    qs[i][dd] = s;
  }
  for (int e = t; e < 48 * 64; e += 256) {
    int j = e >> 6, dd = e & 63;
    float s = bk[h * 64 + dd];
    const float* r = xt + (b * 48 + j) * 64;
    #pragma unroll 8
    for (int c = 0; c < 64; ++c) s += r[c] * Wk[c * 512 + h * 64 + dd];
    ks_[j][dd] = s;
  }
  __syncthreads();
  for (int e = t; e < 24 * 48; e += 256) {
    int i = e / 48, j = e - i * 48;
    float s = 0.f;
    #pragma unroll 8
    for (int dd = 0; dd < 64; ++dd) s += qs[i][dd] * ks_[j][dd];
    sc[i][j] = s * 0.125f;                   // / sqrt(64)
  }
  __syncthreads();
  if (t < 32) {
    int i = t;
    ushort* orow = attnp + ((size_t)bh * 32 + i) * 64;
    if (i < 24) {
      float mx = -1e30f;
      for (int j = 0; j < 48; ++j) mx = fmaxf(mx, sc[i][j]);
      float sum = 0.f;
      for (int j = 0; j < 48; ++j) { float e = expf(sc[i][j] - mx); sc[i][j] = e; sum += e; }
      float inv = 1.f / sum;
      for (int j = 0; j < 48; ++j) orow[j] = f2bf(sc[i][j] * inv);
      for (int j = 48; j < 64; ++j) orow[j] = 0;
    } else {
      for (int j = 0; j < 64; ++j) orow[j] = 0;
    }
  }
}

// ---- main fused kernel: TWO nodes per block ----
// 512 threads / 8 waves; wave = (g=node, w4=hd32-chunk).
// LDS: two A-tiles [48][512] bf16 swizzled = 96 KB. W2 streamed once per
// block (covers 2 nodes -> half the L2/L3 B-traffic per node), 3-deep
// register prefetch. Stage-2 register-only. ONE __syncthreads per block.
#define A_TILE 49152

__global__ __launch_bounds__(512, 1) void main_kernel(
    const float* __restrict__ EH, const ushort* __restrict__ W2,
    const ushort* __restrict__ attnp, const float* __restrict__ bv,
    float* __restrict__ out) {
  __shared__ __align__(128) char smem[98304];
  int bid = blockIdx.x;
  int b = bid >> 9, np = bid & 511;          // nodes np*2, np*2+1
  int t = threadIdx.x;
  int lane = t & 63, w = t >> 6;
  int g = w >> 2, w4 = w & 3;                // node, hd32-chunk
  int rowl = lane & 15;
  int colb = (lane >> 4) << 3;               // K=32 fragment k-offset (elements)
  int colb16 = (lane >> 4) << 2;             // K=16 fragment k-offset (elements)
  const char* atile = smem + g * A_TILE;

  // hoist bv: bvr[ch][nn]
  float bvr[4][2];
  #pragma unroll
  for (int c = 0; c < 4; ++c)
    #pragma unroll
    for (int nn = 0; nn < 2; ++nn)
      bvr[c][nn] = bv[c * 128 + w4 * 32 + nn * 16 + rowl];

  // per-(ch,w4) W2 panel: 16384 ushorts; per-kb: 2048; frag: 512
  const ushort* wbase = W2 + (size_t)w4 * 16384 + lane * 8;

  // prologue: 3-deep prefetch of ck=0,1,2 — in flight during the A-stage
  short8 b0[4], b1[4], b2[4];
  #pragma unroll
  for (int f = 0; f < 4; ++f) b0[f] = *(const short8*)(wbase + f * 512);
  #pragma unroll
  for (int f = 0; f < 4; ++f) b1[f] = *(const short8*)(wbase + 2048 + f * 512);
  #pragma unroll
  for (int f = 0; f < 4; ++f) b2[f] = *(const short8*)(wbase + 4096 + f * 512);

  // stage A: each 256-thread half stages its node (adjacent n -> 4KB segments)
  {
    int tt = t & 255, gs = t >> 8;
    const float* ehb = EH + (((size_t)b * Tt) * Nn + (np * 2 + gs)) * Hh;
    char* dst = smem + gs * A_TILE;
    #pragma unroll 8
    for (int it = 0; it < 24; ++it) {
      int f = it * 256 + tt;                 // 48 rows * 128 float4
      int j = f >> 7, c4 = f & 127;
      float4 v = *(const float4*)(ehb + (size_t)j * (Nn * Hh) + c4 * 4);
      uint2 p;
      p.x = (uint)f2bf(v.x) | ((uint)f2bf(v.y) << 16);
      p.y = (uint)f2bf(v.z) | ((uint)f2bf(v.w) << 16);
      int off = (j << 10) + (c4 << 3);
      off ^= (j & 7) << 4;
      *(uint2*)(dst + off) = p;
    }
  }
  __syncthreads();   // the ONLY barrier: both A-tiles visible

  f32x4 acc[3][2] = {};
  #pragma unroll
  for (int ck = 0; ck < 32; ++ck) {
    const int kb = ck & 7;
    // 3-deep prefetch: issue loads for ck+3 (all indices compile-time)
    short8 bnext[4];
    if (ck < 29) {
      const int ck3 = ck + 3;
      const ushort* wp3 = wbase + (size_t)((ck3 >> 3) * 4) * 16384 + (ck3 & 7) * 2048;
      #pragma unroll
      for (int f = 0; f < 4; ++f) bnext[f] = *(const short8*)(wp3 + f * 512);
    }
    // A fragments for this kb from this wave's node tile: 6 ds_read_b128
    short8 af[2][3];
    #pragma unroll
    for (int ki = 0; ki < 2; ++ki) {
      int kc = kb * 64 + ki * 32 + colb;
      #pragma unroll
      for (int m = 0; m < 3; ++m) {
        int j = m * 16 + rowl;
        int off = (j << 10) + (kc << 1);
        off ^= (j & 7) << 4;
        af[ki][m] = *(const short8*)(atile + off);
      }
    }
    // 12 MFMA on b0 (current)
    __builtin_amdgcn_s_setprio(1);
    #pragma unroll
    for (int m = 0; m < 3; ++m) {
      acc[m][0] = __builtin_amdgcn_mfma_f32_16x16x32_bf16(af[0][m], b0[0], acc[m][0], 0, 0, 0);
      acc[m][1] = __builtin_amdgcn_mfma_f32_16x16x32_bf16(af[0][m], b0[1], acc[m][1], 0, 0, 0);
    }
    #pragma unroll
    for (int m = 0; m < 3; ++m) {
      acc[m][0] = __builtin_amdgcn_mfma_f32_16x16x32_bf16(af[1][m], b0[2], acc[m][0], 0, 0, 0);
      acc[m][1] = __builtin_amdgcn_mfma_f32_16x16x32_bf16(af[1][m], b0[3], acc[m][1], 0, 0, 0);
    }
    __builtin_amdgcn_s_setprio(0);
    // rotate (SSA renaming under full unroll)
    #pragma unroll
    for (int f = 0; f < 4; ++f) { b0[f] = b1[f]; b1[f] = b2[f]; }
    if (ck < 29) {
      #pragma unroll
      for (int f = 0; f < 4; ++f) b2[f] = bnext[f];
    }

    // end of a ch: stage-2 (register-only) + store, then reset acc
    if (kb == 7) {
      const int ch = ck >> 3;
      int h = 2 * ch + (w4 >> 1);
      const ushort* arow = attnp + ((size_t)(b * 8 + h) * 32) * 64;
      int n = np * 2 + g;
      f32x4 x[2][2] = {};
      #pragma unroll
      for (int m = 0; m < 3; ++m) {
        bf16x4 pa[2];
        #pragma unroll
        for (int itl = 0; itl < 2; ++itl)
          pa[itl] = *(const bf16x4*)(arow + (itl * 16 + rowl) * 64 + m * 16 + colb16);
        #pragma unroll
        for (int nn = 0; nn < 2; ++nn) {
          bf16x4 vbq;
          vbq[0] = (short)f2bf(acc[m][nn][0]);
          vbq[1] = (short)f2bf(acc[m][nn][1]);
          vbq[2] = (short)f2bf(acc[m][nn][2]);
          vbq[3] = (short)f2bf(acc[m][nn][3]);
          x[0][nn] = mfma16(pa[0], vbq, x[0][nn]);
          x[1][nn] = mfma16(pa[1], vbq, x[1][nn]);
        }
      }
      #pragma unroll
      for (int itl = 0; itl < 2; ++itl) {
        int ib = itl * 16 + ((lane >> 4) << 2);
        #pragma unroll
        for (int nn = 0; nn < 2; ++nn) {
          int hd = ch * 128 + w4 * 32 + nn * 16 + rowl;
          float bvv = bvr[ch][nn];
          #pragma unroll
          for (int r = 0; r < 4; ++r) {
            int i = ib + r;
            if (i < 24)
              out[(((size_t)b * HZ + i) * Nn + n) * Hh + hd] = x[itl][nn][r] + bvv;
          }
        }
      }
      #pragma unroll
      for (int m = 0; m < 3; ++m)
        #pragma unroll
        for (int nn = 0; nn < 2; ++nn)
          acc[m][nn] = f32x4{0.f, 0.f, 0.f, 0.f};
    }
  }
}

extern "C" void kernel_launch(void* const* d_in, const int* in_sizes, int n_in,
                              void* d_out, int out_size, void* d_ws, size_t ws_size,
                              hipStream_t stream) {
  (void)in_sizes; (void)n_in; (void)out_size; (void)ws_size;
  const float* EH = (const float*)d_in[0];
  const float* xt = (const float*)d_in[1];
  const float* tt = (const float*)d_in[2];
  const float* Wq = (const float*)d_in[3];
  const float* bq = (const float*)d_in[4];
  const float* Wk = (const float*)d_in[5];
  const float* bk = (const float*)d_in[6];
  const float* Wv = (const float*)d_in[7];
  const float* bv = (const float*)d_in[8];
  float* out = (float*)d_out;
  ushort* W2 = (ushort*)d_ws;                                    // 512 KB
  ushort* attnp = (ushort*)((char*)d_ws + 512 * 1024);           // 256 KB

  wvt2_kernel<<<1024, 256, 0, stream>>>(Wv, W2);
  attn_kernel<<<64, 256, 0, stream>>>(xt, tt, Wq, bq, Wk, bk, attnp);
  main_kernel<<<4096, 512, 0, stream>>>(EH, W2, attnp, bv, out);
}